// Round 8
// baseline (350.093 us; speedup 1.0000x reference)
//
#include <hip/hip_runtime.h>
#include <hip/hip_bf16.h>

#define C 256
#define BM 64
#define BN 128
#define BK 32
#define NSTEP 40   // K = 5*256 / 32

typedef __attribute__((ext_vector_type(8))) short bf16x8;
typedef __attribute__((ext_vector_type(4))) float f32x4;
typedef __attribute__((ext_vector_type(4))) unsigned short us4;

#define GLL16(g, l)                                                         \
  __builtin_amdgcn_global_load_lds(                                         \
      (const __attribute__((address_space(1))) void*)(g),                   \
      (__attribute__((address_space(3))) void*)(l), 16, 0, 0)

__device__ __forceinline__ float bf2f(unsigned short u) {
  return __uint_as_float(((unsigned int)u) << 16);
}
__device__ __forceinline__ unsigned short f2bf(float f) {
  unsigned int x = __float_as_uint(f);
  unsigned int lsb = (x >> 16) & 1u;
  x += 0x7fffu + lsb;  // round-to-nearest-even
  return (unsigned short)(x >> 16);
}

// WT[m][c][k] = bf16(W_m[k][c]); m=0 -> root, m=1..4 -> rel r
__global__ void k_prep_w(const float* __restrict__ rel, const float* __restrict__ root,
                         unsigned short* __restrict__ WT) {
  int b = blockIdx.x;
  int m = b >> 8;
  int c = b & 255;
  int k = threadIdx.x;
  const float* W = (m == 0) ? root : (rel + (size_t)(m - 1) * C * C);
  WT[(size_t)m * C * C + (size_t)c * C + k] = f2bf(W[(size_t)k * C + c]);
}

__global__ void k_cvt_x(const float* __restrict__ X, unsigned short* __restrict__ Xbf,
                        int n_elem, int total) {
  int i = (blockIdx.x * blockDim.x + threadIdx.x) * 4;
  if (i >= total) return;
  us4 o;
  if (i < n_elem) {
    const float4 v = *reinterpret_cast<const float4*>(X + i);
    o.x = f2bf(v.x); o.y = f2bf(v.y); o.z = f2bf(v.z); o.w = f2bf(v.w);
  } else {
    o.x = 0; o.y = 0; o.z = 0; o.w = 0;   // zero pad rows
  }
  *reinterpret_cast<us4*>(Xbf + i) = o;
}

__global__ void k_hist(const int* __restrict__ edst, int* __restrict__ cnt, int E) {
  int e = blockIdx.x * blockDim.x + threadIdx.x;
  if (e < E) atomicAdd(cnt + edst[e], 1);
}

__global__ void k_scan1(const int* __restrict__ cnt, int* __restrict__ rp,
                        int* __restrict__ bsum, int n) {
  __shared__ int s[512];
  int t = threadIdx.x;
  int i = blockIdx.x * 512 + t;
  int v = (i < n) ? cnt[i] : 0;
  s[t] = v;
  __syncthreads();
  for (int off = 1; off < 512; off <<= 1) {
    int add = (t >= off) ? s[t - off] : 0;
    __syncthreads();
    s[t] += add;
    __syncthreads();
  }
  if (i < n) rp[i] = s[t] - v;
  if (t == 511) bsum[blockIdx.x] = s[511];
}

__global__ void k_scan2(const int* __restrict__ bsum, int* __restrict__ boff,
                        int* __restrict__ rp, int nb, int n) {
  if (threadIdx.x == 0) {
    int run = 0;
    for (int b = 0; b < nb; ++b) { boff[b] = run; run += bsum[b]; }
    rp[n] = run;
  }
}

// also writes cursor (no d2d memcpy needed)
__global__ void k_scan3(int* __restrict__ rp, const int* __restrict__ boff,
                        int* __restrict__ cursor, int n) {
  int i = blockIdx.x * 512 + threadIdx.x;
  if (i < n) {
    int v = rp[i] + boff[blockIdx.x];
    rp[i] = v;
    cursor[i] = v;
  }
}

__global__ void k_fill(const int* __restrict__ esrc, const int* __restrict__ edst,
                       const int* __restrict__ etype, int* __restrict__ cursor,
                       unsigned int* __restrict__ sorted, int E) {
  int e = blockIdx.x * blockDim.x + threadIdx.x;
  if (e >= E) return;
  int d = edst[e];
  int pos = atomicAdd(cursor + d, 1);
  sorted[pos] = (unsigned int)esrc[e] | ((unsigned int)etype[e] << 28);
}

#define ACC(u, v)                                                            \
  do {                                                                       \
    float f0 = bf2f((v).x), f1 = bf2f((v).y), f2 = bf2f((v).z), f3 = bf2f((v).w); \
    switch ((u) >> 28) {                                                     \
      case 0: a0.x += f0; a0.y += f1; a0.z += f2; a0.w += f3; ++c0; break;   \
      case 1: a1.x += f0; a1.y += f1; a1.z += f2; a1.w += f3; ++c1; break;   \
      case 2: a2.x += f0; a2.y += f1; a2.z += f2; a2.w += f3; ++c2; break;   \
      default: a3.x += f0; a3.y += f1; a3.z += f2; a3.w += f3; ++c3; break;  \
    }                                                                        \
  } while (0)

// One wave per dst node; per-relation fp32 mean-accumulate of bf16 X rows.
__global__ void k_gather(const unsigned short* __restrict__ Xbf,
                         const unsigned int* __restrict__ sorted,
                         const int* __restrict__ rp,
                         unsigned short* __restrict__ agm,
                         int N, int rowsPad) {
  int wave = threadIdx.x >> 6;
  int lane = threadIdx.x & 63;
  int dst = blockIdx.x * 4 + wave;
  if (dst >= rowsPad) return;

  if (dst >= N) {   // pad rows: zero so GEMM reads finite data
    us4 z; z.x = 0; z.y = 0; z.z = 0; z.w = 0;
    for (int r = 0; r < 4; ++r)
      *reinterpret_cast<us4*>(agm + ((size_t)r * rowsPad + dst) * C + lane * 4) = z;
    return;
  }

  float4 a0 = make_float4(0, 0, 0, 0), a1 = a0, a2 = a0, a3 = a0;
  int c0 = 0, c1 = 0, c2 = 0, c3 = 0;
  int s = rp[dst], e2 = rp[dst + 1];
  const us4* Xv = reinterpret_cast<const us4*>(Xbf);

  int e = s;
  for (; e + 8 <= e2; e += 8) {
    unsigned int u0 = sorted[e],     u1 = sorted[e + 1], u2 = sorted[e + 2], u3 = sorted[e + 3];
    unsigned int u4 = sorted[e + 4], u5 = sorted[e + 5], u6 = sorted[e + 6], u7 = sorted[e + 7];
    us4 v0 = Xv[(size_t)(u0 & 0x0FFFFFFFu) * 64 + lane];
    us4 v1 = Xv[(size_t)(u1 & 0x0FFFFFFFu) * 64 + lane];
    us4 v2 = Xv[(size_t)(u2 & 0x0FFFFFFFu) * 64 + lane];
    us4 v3 = Xv[(size_t)(u3 & 0x0FFFFFFFu) * 64 + lane];
    us4 v4 = Xv[(size_t)(u4 & 0x0FFFFFFFu) * 64 + lane];
    us4 v5 = Xv[(size_t)(u5 & 0x0FFFFFFFu) * 64 + lane];
    us4 v6 = Xv[(size_t)(u6 & 0x0FFFFFFFu) * 64 + lane];
    us4 v7 = Xv[(size_t)(u7 & 0x0FFFFFFFu) * 64 + lane];
    ACC(u0, v0); ACC(u1, v1); ACC(u2, v2); ACC(u3, v3);
    ACC(u4, v4); ACC(u5, v5); ACC(u6, v6); ACC(u7, v7);
  }
  for (; e + 4 <= e2; e += 4) {
    unsigned int u0 = sorted[e], u1 = sorted[e + 1], u2 = sorted[e + 2], u3 = sorted[e + 3];
    us4 v0 = Xv[(size_t)(u0 & 0x0FFFFFFFu) * 64 + lane];
    us4 v1 = Xv[(size_t)(u1 & 0x0FFFFFFFu) * 64 + lane];
    us4 v2 = Xv[(size_t)(u2 & 0x0FFFFFFFu) * 64 + lane];
    us4 v3 = Xv[(size_t)(u3 & 0x0FFFFFFFu) * 64 + lane];
    ACC(u0, v0); ACC(u1, v1); ACC(u2, v2); ACC(u3, v3);
  }
  for (; e < e2; ++e) {
    unsigned int u = sorted[e];
    us4 v = Xv[(size_t)(u & 0x0FFFFFFFu) * 64 + lane];
    ACC(u, v);
  }

  float s0 = 1.0f / (float)max(c0, 1);
  float s1 = 1.0f / (float)max(c1, 1);
  float s2 = 1.0f / (float)max(c2, 1);
  float s3 = 1.0f / (float)max(c3, 1);
  us4 o;
  size_t base = (size_t)dst * C + lane * 4;
  o.x = f2bf(a0.x * s0); o.y = f2bf(a0.y * s0); o.z = f2bf(a0.z * s0); o.w = f2bf(a0.w * s0);
  *reinterpret_cast<us4*>(agm + base) = o;
  o.x = f2bf(a1.x * s1); o.y = f2bf(a1.y * s1); o.z = f2bf(a1.z * s1); o.w = f2bf(a1.w * s1);
  *reinterpret_cast<us4*>(agm + (size_t)rowsPad * C + base) = o;
  o.x = f2bf(a2.x * s2); o.y = f2bf(a2.y * s2); o.z = f2bf(a2.z * s2); o.w = f2bf(a2.w * s2);
  *reinterpret_cast<us4*>(agm + (size_t)2 * rowsPad * C + base) = o;
  o.x = f2bf(a3.x * s3); o.y = f2bf(a3.y * s3); o.z = f2bf(a3.z * s3); o.w = f2bf(a3.w * s3);
  *reinterpret_cast<us4*>(agm + (size_t)3 * rowsPad * C + base) = o;
}

// GEMM: out = A_all @ WT^T + bias.  BM=64 x BN=128, 4 waves (wave tile 32x64).
// A: proven GLL16 2-phase dbuf, linear LDS dest + inverse-swizzled source +
//    swizzled ds_read (2-way max). B: direct global->register prefetch from
//    L2-resident WT (640 KB). One barrier per K-step.
__global__ __launch_bounds__(256) void k_gemm(
    const unsigned short* __restrict__ Aall, const unsigned short* __restrict__ WT,
    const float* __restrict__ bias, float* __restrict__ out, int N, int rowsPad) {
  __shared__ unsigned short lds_a[2][BM * BK];   // 2 x 4KB
  int tid = threadIdx.x;
  int wave = tid >> 6, lane = tid & 63;

  // bijective chunked XCD swizzle: (m, n=0/1) pairs share an XCD's L2
  int nwg = gridDim.x, orig = blockIdx.x;
  int q = nwg >> 3, r = nwg & 7;
  int xcd = orig & 7, lin = orig >> 3;
  int wgid = (xcd < r ? xcd * (q + 1) : r * (q + 1) + (xcd - r) * q) + lin;
  int mblk = wgid >> 1, nblk = wgid & 1;
  int row0 = mblk * BM, col0 = nblk * BN;
  int wr = wave >> 1, wc = wave & 1, lcol = lane & 15;

  // A staging geometry (R4-proven): wave w stages 1KB = 16 rows
  int offA = wave * 1024 + lane * 16;
  int arS = offA >> 6;                               // tile row
  int alg8 = ((((offA >> 4) & 3) ^ ((arS >> 1) & 3))) * 8;   // src elem offset

  // A ds_read byte offsets (swizzled, loop-invariant)
  int aoff[2];
  int kb = (lane >> 4) * 16;
#pragma unroll
  for (int i = 0; i < 2; ++i) {
    int ar = wr * 32 + i * 16 + lcol;
    aoff[i] = ar * 64 + (kb ^ (((ar >> 1) & 3) << 4));
  }
  // B columns owned by this lane
  int bcol[4];
#pragma unroll
  for (int j = 0; j < 4; ++j) bcol[j] = col0 + wc * 64 + j * 16 + lcol;
  int kq = (lane >> 4) * 8;

  f32x4 acc[2][4];
#pragma unroll
  for (int i = 0; i < 2; ++i)
#pragma unroll
    for (int j = 0; j < 4; ++j) {
      f32x4 z; z[0] = 0.f; z[1] = 0.f; z[2] = 0.f; z[3] = 0.f;
      acc[i][j] = z;
    }

  auto stageA = [&](int buf, int ks) {
    int m = ks >> 3, kk = (ks & 7) * BK;
    const unsigned short* Ab = Aall + (size_t)m * rowsPad * C + kk;
    GLL16(Ab + (size_t)(row0 + arS) * C + alg8, (char*)&lds_a[buf][0] + wave * 1024);
  };
  auto loadB = [&](int ks, int j) {
    int m = ks >> 3, kk = (ks & 7) * BK;
    return *reinterpret_cast<const bf16x8*>(
        WT + (size_t)m * 65536 + (size_t)bcol[j] * 256 + kk + kq);
  };

  // prologue: A(0) staged, B(0) in regs
  stageA(0, 0);
  bf16x8 b0 = loadB(0, 0), b1 = loadB(0, 1), b2 = loadB(0, 2), b3 = loadB(0, 3);
  __syncthreads();

#pragma unroll 1
  for (int ks = 0; ks < NSTEP; ++ks) {
    int cur = ks & 1;
    int ks1 = (ks + 1 < NSTEP) ? ks + 1 : NSTEP - 1;
    if (ks + 1 < NSTEP) stageA(cur ^ 1, ks + 1);    // next A tile in flight
    bf16x8 n0 = loadB(ks1, 0), n1 = loadB(ks1, 1), n2 = loadB(ks1, 2), n3 = loadB(ks1, 3);
    bf16x8 af0 = *reinterpret_cast<const bf16x8*>((const char*)&lds_a[cur][0] + aoff[0]);
    bf16x8 af1 = *reinterpret_cast<const bf16x8*>((const char*)&lds_a[cur][0] + aoff[1]);
    acc[0][0] = __builtin_amdgcn_mfma_f32_16x16x32_bf16(af0, b0, acc[0][0], 0, 0, 0);
    acc[0][1] = __builtin_amdgcn_mfma_f32_16x16x32_bf16(af0, b1, acc[0][1], 0, 0, 0);
    acc[0][2] = __builtin_amdgcn_mfma_f32_16x16x32_bf16(af0, b2, acc[0][2], 0, 0, 0);
    acc[0][3] = __builtin_amdgcn_mfma_f32_16x16x32_bf16(af0, b3, acc[0][3], 0, 0, 0);
    acc[1][0] = __builtin_amdgcn_mfma_f32_16x16x32_bf16(af1, b0, acc[1][0], 0, 0, 0);
    acc[1][1] = __builtin_amdgcn_mfma_f32_16x16x32_bf16(af1, b1, acc[1][1], 0, 0, 0);
    acc[1][2] = __builtin_amdgcn_mfma_f32_16x16x32_bf16(af1, b2, acc[1][2], 0, 0, 0);
    acc[1][3] = __builtin_amdgcn_mfma_f32_16x16x32_bf16(af1, b3, acc[1][3], 0, 0, 0);
    __syncthreads();
    b0 = n0; b1 = n1; b2 = n2; b3 = n3;
  }

  int lrow4 = (lane >> 4) * 4;
#pragma unroll
  for (int mr = 0; mr < 2; ++mr) {
#pragma unroll
    for (int reg = 0; reg < 4; ++reg) {
      int rowg = row0 + wr * 32 + mr * 16 + lrow4 + reg;
      if (rowg < N) {
#pragma unroll
        for (int nc = 0; nc < 4; ++nc) {
          int colg = col0 + wc * 64 + nc * 16 + lcol;
          out[(size_t)rowg * C + colg] = acc[mr][nc][reg] + bias[colg];
        }
      }
    }
  }
}

// Gate: a = sigmoid(u0.w1 + x.w2 + b); h = tanh(u0)*a + x*(1-a). One wave/node.
__global__ void k_gate(const float* __restrict__ X, const float* __restrict__ aw,
                       const float* __restrict__ ab, float* __restrict__ out, int N) {
  int wave = threadIdx.x >> 6, lane = threadIdx.x & 63;
  int node = blockIdx.x * 4 + wave;
  if (node >= N) return;
  const float4* u4 = reinterpret_cast<const float4*>(out + (size_t)node * C);
  const float4* x4 = reinterpret_cast<const float4*>(X + (size_t)node * C);
  float4 u = u4[lane], x = x4[lane];
  const float4* w = reinterpret_cast<const float4*>(aw);
  float4 w1 = w[lane], w2 = w[64 + lane];
  float p = u.x * w1.x + u.y * w1.y + u.z * w1.z + u.w * w1.w
          + x.x * w2.x + x.y * w2.y + x.z * w2.z + x.w * w2.w;
#pragma unroll
  for (int off = 32; off >= 1; off >>= 1) p += __shfl_xor(p, off);
  float a = 1.0f / (1.0f + expf(-(p + ab[0])));
  float b = 1.0f - a;
  float4 h;
  h.x = tanhf(u.x) * a + x.x * b;
  h.y = tanhf(u.y) * a + x.y * b;
  h.z = tanhf(u.z) * a + x.z * b;
  h.w = tanhf(u.w) * a + x.w * b;
  reinterpret_cast<float4*>(out + (size_t)node * C)[lane] = h;
}

extern "C" void kernel_launch(void* const* d_in, const int* in_sizes, int n_in,
                              void* d_out, int out_size, void* d_ws, size_t ws_size,
                              hipStream_t stream) {
  const float* X     = (const float*)d_in[0];
  const int*   eidx  = (const int*)d_in[1];
  const int*   etype = (const int*)d_in[2];
  const float* rel   = (const float*)d_in[3];
  const float* root  = (const float*)d_in[4];
  const float* bias  = (const float*)d_in[5];
  const float* attw  = (const float*)d_in[6];
  const float* ab    = (const float*)d_in[7];
  float* out = (float*)d_out;

  int N = in_sizes[0] / C;                // 50000
  int E = in_sizes[2];                    // 800000
  int rowsPad = ((N + 127) / 128) * 128;  // 50048
  const int* esrc = eidx;
  const int* edst = eidx + E;

  char* w = (char*)d_ws;
  size_t off = 0;
  auto alloc = [&](size_t bytes) -> void* {
    void* p = w + off;
    off += (bytes + 255) & ~(size_t)255;
    return p;
  };
  unsigned short* Aall = (unsigned short*)alloc((size_t)5 * rowsPad * C * 2);
  unsigned short* Xbf  = Aall;
  unsigned short* agm  = Aall + (size_t)rowsPad * C;
  unsigned short* WT   = (unsigned short*)alloc((size_t)5 * C * C * 2);
  int* cnt    = (int*)alloc((size_t)N * 4);
  int* rp     = (int*)alloc((size_t)(N + 1) * 4);
  int* cursor = (int*)alloc((size_t)N * 4);
  int* bsum   = (int*)alloc(1024);
  int* boffb  = (int*)alloc(1024);
  unsigned int* sorted = (unsigned int*)alloc((size_t)E * 4);

  hipMemsetAsync(cnt, 0, (size_t)N * 4, stream);
  k_prep_w<<<5 * C, C, 0, stream>>>(rel, root, WT);
  k_cvt_x<<<(rowsPad * C / 4 + 255) / 256, 256, 0, stream>>>(X, Xbf, N * C, rowsPad * C);
  k_hist<<<(E + 255) / 256, 256, 0, stream>>>(edst, cnt, E);
  int NB = (N + 511) / 512;
  k_scan1<<<NB, 512, 0, stream>>>(cnt, rp, bsum, N);
  k_scan2<<<1, 64, 0, stream>>>(bsum, boffb, rp, NB, N);
  k_scan3<<<NB, 512, 0, stream>>>(rp, boffb, cursor, N);
  k_fill<<<(E + 255) / 256, 256, 0, stream>>>(esrc, edst, etype, cursor, sorted, E);
  k_gather<<<rowsPad / 4, 256, 0, stream>>>(Xbf, sorted, rp, agm, N, rowsPad);
  k_gemm<<<(rowsPad / BM) * 2, 256, 0, stream>>>(Aall, WT, bias, out, N, rowsPad);
  k_gate<<<(N + 3) / 4, 256, 0, stream>>>(X, attw, ab, out, N);
}

// Round 9
// 272.195 us; speedup vs baseline: 1.2862x; 1.2862x over previous
//
#include <hip/hip_runtime.h>
#include <hip/hip_bf16.h>

#define C 256
#define KTOT 1280
#define BM 64
#define BN 128
#define BK 32
#define NSTEP 40   // K = 1280 / 32

typedef __attribute__((ext_vector_type(8))) short bf16x8;
typedef __attribute__((ext_vector_type(4))) float f32x4;
typedef __attribute__((ext_vector_type(4))) unsigned short us4;

#define GLL16(g, l)                                                         \
  __builtin_amdgcn_global_load_lds(                                         \
      (const __attribute__((address_space(1))) void*)(g),                   \
      (__attribute__((address_space(3))) void*)(l), 16, 0, 0)

__device__ __forceinline__ float bf2f(unsigned short u) {
  return __uint_as_float(((unsigned int)u) << 16);
}
__device__ __forceinline__ unsigned short f2bf(float f) {
  unsigned int x = __float_as_uint(f);
  unsigned int lsb = (x >> 16) & 1u;
  x += 0x7fffu + lsb;  // round-to-nearest-even
  return (unsigned short)(x >> 16);
}

// Fused prep: WT[c][m*256+k] = bf16(W_m[k][c]); Xbf rows (k-interleaved layout,
// X occupies cols 0..255 of Aall[row][1280]); cnt zeroing.
// blocks [0,1280): WT | [1280,1280+rowsPad/4): cvt | rest: cnt
__global__ void k_pre(const float* __restrict__ X, const float* __restrict__ rel,
                      const float* __restrict__ root, unsigned short* __restrict__ Aall,
                      unsigned short* __restrict__ WT, int* __restrict__ cnt,
                      int N, int rowsPad) {
  int b = blockIdx.x, t = threadIdx.x;
  if (b < 1280) {                       // m = b>>8, c = b&255, k = t
    int m = b >> 8, c = b & 255;
    const float* W = (m == 0) ? root : (rel + (size_t)(m - 1) * C * C);
    WT[(size_t)c * KTOT + m * C + t] = f2bf(W[(size_t)t * C + c]);
  } else if (b < 1280 + (rowsPad >> 2)) {
    int row = (b - 1280) * 4 + (t >> 6);
    int lane = t & 63;
    us4 o;
    if (row < N) {
      float4 v = reinterpret_cast<const float4*>(X + (size_t)row * C)[lane];
      o.x = f2bf(v.x); o.y = f2bf(v.y); o.z = f2bf(v.z); o.w = f2bf(v.w);
    } else { o.x = 0; o.y = 0; o.z = 0; o.w = 0; }
    *reinterpret_cast<us4*>(Aall + (size_t)row * KTOT + lane * 4) = o;
  } else {
    int i = (b - 1280 - (rowsPad >> 2)) * 256 + t;
    if (i < N) cnt[i] = 0;
  }
}

__global__ void k_hist(const int* __restrict__ edst, int* __restrict__ cnt, int E) {
  int e = blockIdx.x * blockDim.x + threadIdx.x;
  if (e < E) atomicAdd(cnt + edst[e], 1);
}

__global__ void k_scan1(const int* __restrict__ cnt, int* __restrict__ rp,
                        int* __restrict__ bsum, int n) {
  __shared__ int s[512];
  int t = threadIdx.x;
  int i = blockIdx.x * 512 + t;
  int v = (i < n) ? cnt[i] : 0;
  s[t] = v;
  __syncthreads();
  for (int off = 1; off < 512; off <<= 1) {
    int add = (t >= off) ? s[t - off] : 0;
    __syncthreads();
    s[t] += add;
    __syncthreads();
  }
  if (i < n) rp[i] = s[t] - v;
  if (t == 511) bsum[blockIdx.x] = s[511];
}

__global__ void k_scan2(const int* __restrict__ bsum, int* __restrict__ boff,
                        int* __restrict__ rp, int nb, int n) {
  if (threadIdx.x == 0) {
    int run = 0;
    for (int b = 0; b < nb; ++b) { boff[b] = run; run += bsum[b]; }
    rp[n] = run;
  }
}

__global__ void k_scan3(int* __restrict__ rp, const int* __restrict__ boff,
                        int* __restrict__ cursor, int n) {
  int i = blockIdx.x * 512 + threadIdx.x;
  if (i < n) {
    int v = rp[i] + boff[blockIdx.x];
    rp[i] = v;
    cursor[i] = v;
  }
}

__global__ void k_fill(const int* __restrict__ esrc, const int* __restrict__ edst,
                       const int* __restrict__ etype, int* __restrict__ cursor,
                       unsigned int* __restrict__ sorted, int E) {
  int e = blockIdx.x * blockDim.x + threadIdx.x;
  if (e >= E) return;
  int d = edst[e];
  int pos = atomicAdd(cursor + d, 1);
  sorted[pos] = (unsigned int)esrc[e] | ((unsigned int)etype[e] << 28);
}

#define ACC(u, v)                                                            \
  do {                                                                       \
    float f0 = bf2f((v).x), f1 = bf2f((v).y), f2 = bf2f((v).z), f3 = bf2f((v).w); \
    switch ((u) >> 28) {                                                     \
      case 0: a0.x += f0; a0.y += f1; a0.z += f2; a0.w += f3; ++c0; break;   \
      case 1: a1.x += f0; a1.y += f1; a1.z += f2; a1.w += f3; ++c1; break;   \
      case 2: a2.x += f0; a2.y += f1; a2.z += f2; a2.w += f3; ++c2; break;   \
      default: a3.x += f0; a3.y += f1; a3.z += f2; a3.w += f3; ++c3; break;  \
    }                                                                        \
  } while (0)

// One wave per dst node; per-relation fp32 mean-accumulate of X rows (cols
// 0..255 of Aall); writes means into cols (r+1)*256.. of Aall[dst]. Unroll x8.
__global__ void k_gather(unsigned short* __restrict__ Aall,
                         const unsigned int* __restrict__ sorted,
                         const int* __restrict__ rp, int N, int rowsPad) {
  int wave = threadIdx.x >> 6;
  int lane = threadIdx.x & 63;
  int dst = blockIdx.x * 4 + wave;
  if (dst >= rowsPad) return;
  us4* agv = reinterpret_cast<us4*>(Aall);     // us4 = 4 shorts = 8B; row = 320 us4

  if (dst >= N) {   // pad rows: zero relation segments (X segment zeroed in k_pre)
    us4 z; z.x = 0; z.y = 0; z.z = 0; z.w = 0;
    for (int r = 1; r <= 4; ++r)
      agv[(size_t)dst * 320 + r * 64 + lane] = z;
    return;
  }

  float4 a0 = make_float4(0, 0, 0, 0), a1 = a0, a2 = a0, a3 = a0;
  int c0 = 0, c1 = 0, c2 = 0, c3 = 0;
  int s = rp[dst], e2 = rp[dst + 1];

  int e = s;
  for (; e + 8 <= e2; e += 8) {
    unsigned int u0 = sorted[e],     u1 = sorted[e + 1], u2 = sorted[e + 2], u3 = sorted[e + 3];
    unsigned int u4 = sorted[e + 4], u5 = sorted[e + 5], u6 = sorted[e + 6], u7 = sorted[e + 7];
    us4 v0 = agv[(size_t)(u0 & 0x0FFFFFFFu) * 320 + lane];
    us4 v1 = agv[(size_t)(u1 & 0x0FFFFFFFu) * 320 + lane];
    us4 v2 = agv[(size_t)(u2 & 0x0FFFFFFFu) * 320 + lane];
    us4 v3 = agv[(size_t)(u3 & 0x0FFFFFFFu) * 320 + lane];
    us4 v4 = agv[(size_t)(u4 & 0x0FFFFFFFu) * 320 + lane];
    us4 v5 = agv[(size_t)(u5 & 0x0FFFFFFFu) * 320 + lane];
    us4 v6 = agv[(size_t)(u6 & 0x0FFFFFFFu) * 320 + lane];
    us4 v7 = agv[(size_t)(u7 & 0x0FFFFFFFu) * 320 + lane];
    ACC(u0, v0); ACC(u1, v1); ACC(u2, v2); ACC(u3, v3);
    ACC(u4, v4); ACC(u5, v5); ACC(u6, v6); ACC(u7, v7);
  }
  for (; e + 4 <= e2; e += 4) {
    unsigned int u0 = sorted[e], u1 = sorted[e + 1], u2 = sorted[e + 2], u3 = sorted[e + 3];
    us4 v0 = agv[(size_t)(u0 & 0x0FFFFFFFu) * 320 + lane];
    us4 v1 = agv[(size_t)(u1 & 0x0FFFFFFFu) * 320 + lane];
    us4 v2 = agv[(size_t)(u2 & 0x0FFFFFFFu) * 320 + lane];
    us4 v3 = agv[(size_t)(u3 & 0x0FFFFFFFu) * 320 + lane];
    ACC(u0, v0); ACC(u1, v1); ACC(u2, v2); ACC(u3, v3);
  }
  for (; e < e2; ++e) {
    unsigned int u = sorted[e];
    us4 v = agv[(size_t)(u & 0x0FFFFFFFu) * 320 + lane];
    ACC(u, v);
  }

  float s0 = 1.0f / (float)max(c0, 1);
  float s1 = 1.0f / (float)max(c1, 1);
  float s2 = 1.0f / (float)max(c2, 1);
  float s3 = 1.0f / (float)max(c3, 1);
  us4 o;
  size_t base = (size_t)dst * 320 + lane;
  o.x = f2bf(a0.x * s0); o.y = f2bf(a0.y * s0); o.z = f2bf(a0.z * s0); o.w = f2bf(a0.w * s0);
  agv[base + 64] = o;
  o.x = f2bf(a1.x * s1); o.y = f2bf(a1.y * s1); o.z = f2bf(a1.z * s1); o.w = f2bf(a1.w * s1);
  agv[base + 128] = o;
  o.x = f2bf(a2.x * s2); o.y = f2bf(a2.y * s2); o.z = f2bf(a2.z * s2); o.w = f2bf(a2.w * s2);
  agv[base + 192] = o;
  o.x = f2bf(a3.x * s3); o.y = f2bf(a3.y * s3); o.z = f2bf(a3.z * s3); o.w = f2bf(a3.w * s3);
  agv[base + 256] = o;
}

// out = Aall @ WT^T + bias over unified K=1280 (k-interleaved layout).
// R4-proven pipeline: 2-phase dbuf, GLL16 staging both operands, one barrier
// per step, 2-way-max XOR swizzle. Per-step address = hoisted base + ks*64B.
__global__ __launch_bounds__(256) void k_gemm(
    const unsigned short* __restrict__ Aall, const unsigned short* __restrict__ WT,
    const float* __restrict__ bias, float* __restrict__ out, int N, int rowsPad) {
  __shared__ unsigned short lds_a[2][BM * BK];   // 2 x 4KB
  __shared__ unsigned short lds_b[2][BN * BK];   // 2 x 8KB
  int tid = threadIdx.x;
  int wave = tid >> 6, lane = tid & 63;

  // bijective chunked XCD swizzle: (m, n=0/1) pairs share an XCD's L2
  int nwg = gridDim.x, orig = blockIdx.x;
  int q = nwg >> 3, r = nwg & 7;
  int xcd = orig & 7, lin = orig >> 3;
  int wgid = (xcd < r ? xcd * (q + 1) : r * (q + 1) + (xcd - r) * q) + lin;
  int mblk = wgid >> 1, nblk = wgid & 1;
  int row0 = mblk * BM, col0 = nblk * BN;
  int wr = wave >> 1, wc = wave & 1, lcol = lane & 15;

  // staging geometry: wave stages A chunk (1KB=16 rows), B chunks 2w,2w+1
  int offA = wave * 1024 + lane * 16;
  int arS = offA >> 6;
  int alg8 = ((((offA >> 4) & 3) ^ ((arS >> 1) & 3))) * 8;
  const unsigned short* aSrc = Aall + (size_t)(row0 + arS) * KTOT + alg8;   // + ks*32
  const unsigned short* bSrc[2];
#pragma unroll
  for (int c2 = 0; c2 < 2; ++c2) {
    int off = (wave * 2 + c2) * 1024 + lane * 16;
    int rr = off >> 6;
    int lg8 = ((((off >> 4) & 3) ^ ((rr >> 1) & 3))) * 8;
    bSrc[c2] = WT + (size_t)(col0 + rr) * KTOT + lg8;                       // + ks*32
  }

  // ds_read byte offsets (swizzled, loop-invariant)
  int aoff[2], boff[4];
  int kb = (lane >> 4) * 16;
#pragma unroll
  for (int i = 0; i < 2; ++i) {
    int ar = wr * 32 + i * 16 + lcol;
    aoff[i] = ar * 64 + (kb ^ (((ar >> 1) & 3) << 4));
  }
#pragma unroll
  for (int j = 0; j < 4; ++j) {
    int bc = wc * 64 + j * 16 + lcol;
    boff[j] = bc * 64 + (kb ^ (((bc >> 1) & 3) << 4));
  }

  f32x4 acc[2][4];
#pragma unroll
  for (int i = 0; i < 2; ++i)
#pragma unroll
    for (int j = 0; j < 4; ++j) {
      f32x4 z; z[0] = 0.f; z[1] = 0.f; z[2] = 0.f; z[3] = 0.f;
      acc[i][j] = z;
    }

  auto stage = [&](int buf, int ks) {
    int kofs = ks * BK;
    GLL16(aSrc + kofs, (char*)&lds_a[buf][0] + wave * 1024);
    GLL16(bSrc[0] + kofs, (char*)&lds_b[buf][0] + (wave * 2) * 1024);
    GLL16(bSrc[1] + kofs, (char*)&lds_b[buf][0] + (wave * 2 + 1) * 1024);
  };

  stage(0, 0);
  __syncthreads();   // tile 0 resident

#pragma unroll 1
  for (int ks = 0; ks < NSTEP; ++ks) {
    int cur = ks & 1;
    if (ks + 1 < NSTEP) stage(cur ^ 1, ks + 1);   // next-tile loads in flight
    bf16x8 af[2], bfr[4];
#pragma unroll
    for (int i = 0; i < 2; ++i)
      af[i] = *reinterpret_cast<const bf16x8*>((const char*)&lds_a[cur][0] + aoff[i]);
#pragma unroll
    for (int j = 0; j < 4; ++j)
      bfr[j] = *reinterpret_cast<const bf16x8*>((const char*)&lds_b[cur][0] + boff[j]);
#pragma unroll
    for (int mr = 0; mr < 2; ++mr)
#pragma unroll
      for (int nc = 0; nc < 4; ++nc)
        acc[mr][nc] = __builtin_amdgcn_mfma_f32_16x16x32_bf16(af[mr], bfr[nc], acc[mr][nc], 0, 0, 0);
    __syncthreads();
  }

  int lrow4 = (lane >> 4) * 4;
#pragma unroll
  for (int mr = 0; mr < 2; ++mr) {
#pragma unroll
    for (int reg = 0; reg < 4; ++reg) {
      int rowg = row0 + wr * 32 + mr * 16 + lrow4 + reg;
      if (rowg < N) {
#pragma unroll
        for (int nc = 0; nc < 4; ++nc) {
          int colg = col0 + wc * 64 + nc * 16 + lcol;
          out[(size_t)rowg * C + colg] = acc[mr][nc][reg] + bias[colg];
        }
      }
    }
  }
}

// Gate: a = sigmoid(u0.w1 + x.w2 + b); h = tanh(u0)*a + x*(1-a). One wave/node.
__global__ void k_gate(const float* __restrict__ X, const float* __restrict__ aw,
                       const float* __restrict__ ab, float* __restrict__ out, int N) {
  int wave = threadIdx.x >> 6, lane = threadIdx.x & 63;
  int node = blockIdx.x * 4 + wave;
  if (node >= N) return;
  const float4* u4 = reinterpret_cast<const float4*>(out + (size_t)node * C);
  const float4* x4 = reinterpret_cast<const float4*>(X + (size_t)node * C);
  float4 u = u4[lane], x = x4[lane];
  const float4* w = reinterpret_cast<const float4*>(aw);
  float4 w1 = w[lane], w2 = w[64 + lane];
  float p = u.x * w1.x + u.y * w1.y + u.z * w1.z + u.w * w1.w
          + x.x * w2.x + x.y * w2.y + x.z * w2.z + x.w * w2.w;
#pragma unroll
  for (int off = 32; off >= 1; off >>= 1) p += __shfl_xor(p, off);
  float a = 1.0f / (1.0f + expf(-(p + ab[0])));
  float b = 1.0f - a;
  float4 h;
  h.x = tanhf(u.x) * a + x.x * b;
  h.y = tanhf(u.y) * a + x.y * b;
  h.z = tanhf(u.z) * a + x.z * b;
  h.w = tanhf(u.w) * a + x.w * b;
  reinterpret_cast<float4*>(out + (size_t)node * C)[lane] = h;
}

extern "C" void kernel_launch(void* const* d_in, const int* in_sizes, int n_in,
                              void* d_out, int out_size, void* d_ws, size_t ws_size,
                              hipStream_t stream) {
  const float* X     = (const float*)d_in[0];
  const int*   eidx  = (const int*)d_in[1];
  const int*   etype = (const int*)d_in[2];
  const float* rel   = (const float*)d_in[3];
  const float* root  = (const float*)d_in[4];
  const float* bias  = (const float*)d_in[5];
  const float* attw  = (const float*)d_in[6];
  const float* ab    = (const float*)d_in[7];
  float* out = (float*)d_out;

  int N = in_sizes[0] / C;                // 50000
  int E = in_sizes[2];                    // 800000
  int rowsPad = ((N + 127) / 128) * 128;  // 50048
  const int* esrc = eidx;
  const int* edst = eidx + E;

  char* w = (char*)d_ws;
  size_t off = 0;
  auto alloc = [&](size_t bytes) -> void* {
    void* p = w + off;
    off += (bytes + 255) & ~(size_t)255;
    return p;
  };
  // Aall[row][1280]: cols 0..255 = X(bf16), (r+1)*256.. = relation-r means
  unsigned short* Aall = (unsigned short*)alloc((size_t)rowsPad * KTOT * 2);
  unsigned short* WT   = (unsigned short*)alloc((size_t)C * KTOT * 2);   // [col][1280]
  int* cnt    = (int*)alloc((size_t)N * 4);
  int* rp     = (int*)alloc((size_t)(N + 1) * 4);
  int* cursor = (int*)alloc((size_t)N * 4);
  int* bsum   = (int*)alloc(1024);
  int* boffb  = (int*)alloc(1024);
  unsigned int* sorted = (unsigned int*)alloc((size_t)E * 4);

  int preBlocks = 1280 + (rowsPad >> 2) + (N + 255) / 256;
  k_pre<<<preBlocks, 256, 0, stream>>>(X, rel, root, Aall, WT, cnt, N, rowsPad);
  k_hist<<<(E + 255) / 256, 256, 0, stream>>>(edst, cnt, E);
  int NB = (N + 511) / 512;
  k_scan1<<<NB, 512, 0, stream>>>(cnt, rp, bsum, N);
  k_scan2<<<1, 64, 0, stream>>>(bsum, boffb, rp, NB, N);
  k_scan3<<<NB, 512, 0, stream>>>(rp, boffb, cursor, N);
  k_fill<<<(E + 255) / 256, 256, 0, stream>>>(esrc, edst, etype, cursor, sorted, E);
  k_gather<<<rowsPad / 4, 256, 0, stream>>>(Aall, sorted, rp, N, rowsPad);
  k_gemm<<<(rowsPad / BM) * 2, 256, 0, stream>>>(Aall, WT, bias, out, N, rowsPad);
  k_gate<<<(N + 3) / 4, 256, 0, stream>>>(X, attw, ab, out, N);
}

// Round 10
// 256.941 us; speedup vs baseline: 1.3625x; 1.0594x over previous
//
#include <hip/hip_runtime.h>
#include <hip/hip_bf16.h>

#define C 256
#define NOUT 1280
#define BK 32

typedef __attribute__((ext_vector_type(8))) short bf16x8;
typedef __attribute__((ext_vector_type(4))) float f32x4;
typedef __attribute__((ext_vector_type(4))) unsigned short us4;

#define GLL16(g, l)                                                         \
  __builtin_amdgcn_global_load_lds(                                         \
      (const __attribute__((address_space(1))) void*)(g),                   \
      (__attribute__((address_space(3))) void*)(l), 16, 0, 0)

__device__ __forceinline__ float bf2f(unsigned short u) {
  return __uint_as_float(((unsigned int)u) << 16);
}
__device__ __forceinline__ unsigned short f2bf(float f) {
  unsigned int x = __float_as_uint(f);
  unsigned int lsb = (x >> 16) & 1u;
  x += 0x7fffu + lsb;  // round-to-nearest-even
  return (unsigned short)(x >> 16);
}

// Fused prep. blocks [0,1280): WT2[n][k] = bf16(W_m[k][c]) with n=m*256+c.
// [1280, 1280+rowsPad/4): X->bf16 rows + ax2[row]=dot(X,w2). rest: cnt=0.
__global__ void k_pre(const float* __restrict__ X, const float* __restrict__ rel,
                      const float* __restrict__ root, const float* __restrict__ attw,
                      unsigned short* __restrict__ Xbf, unsigned short* __restrict__ WT2,
                      float* __restrict__ ax2, int* __restrict__ cnt,
                      int N, int rowsPad) {
  int b = blockIdx.x, t = threadIdx.x;
  if (b < NOUT) {
    int m = b >> 8, c = b & 255;
    const float* W = (m == 0) ? root : (rel + (size_t)(m - 1) * C * C);
    WT2[(size_t)b * C + t] = f2bf(W[(size_t)t * C + c]);
  } else if (b < NOUT + (rowsPad >> 2)) {
    int row = (b - NOUT) * 4 + (t >> 6);
    int lane = t & 63;
    if (row < N) {
      float4 v = reinterpret_cast<const float4*>(X + (size_t)row * C)[lane];
      float4 w2 = reinterpret_cast<const float4*>(attw + C)[lane];
      us4 o;
      o.x = f2bf(v.x); o.y = f2bf(v.y); o.z = f2bf(v.z); o.w = f2bf(v.w);
      reinterpret_cast<us4*>(Xbf)[(size_t)row * 64 + lane] = o;
      float p = v.x * w2.x + v.y * w2.y + v.z * w2.z + v.w * w2.w;
#pragma unroll
      for (int m2 = 32; m2 >= 1; m2 >>= 1) p += __shfl_xor(p, m2);
      if (lane == 0) ax2[row] = p;
    } else if (row < rowsPad) {
      us4 z; z.x = 0; z.y = 0; z.z = 0; z.w = 0;
      reinterpret_cast<us4*>(Xbf)[(size_t)row * 64 + lane] = z;
      if (lane == 0) ax2[row] = 0.f;
    }
  } else {
    int i = (b - NOUT - (rowsPad >> 2)) * 256 + t;
    if (i < N) cnt[i] = 0;
  }
}

__global__ void k_hist(const int* __restrict__ edst, int* __restrict__ cnt, int E) {
  int e = blockIdx.x * blockDim.x + threadIdx.x;
  if (e < E) atomicAdd(cnt + edst[e], 1);
}

__global__ void k_scan1(const int* __restrict__ cnt, int* __restrict__ rp,
                        int* __restrict__ bsum, int n) {
  __shared__ int s[512];
  int t = threadIdx.x;
  int i = blockIdx.x * 512 + t;
  int v = (i < n) ? cnt[i] : 0;
  s[t] = v;
  __syncthreads();
  for (int off = 1; off < 512; off <<= 1) {
    int add = (t >= off) ? s[t - off] : 0;
    __syncthreads();
    s[t] += add;
    __syncthreads();
  }
  if (i < n) rp[i] = s[t] - v;
  if (t == 511) bsum[blockIdx.x] = s[511];
}

__global__ void k_scan2(const int* __restrict__ bsum, int* __restrict__ boff,
                        int* __restrict__ rp, int nb, int n) {
  if (threadIdx.x == 0) {
    int run = 0;
    for (int b = 0; b < nb; ++b) { boff[b] = run; run += bsum[b]; }
    rp[n] = run;
  }
}

__global__ void k_scan3(int* __restrict__ rp, const int* __restrict__ boff,
                        int* __restrict__ cursor, int n) {
  int i = blockIdx.x * 512 + threadIdx.x;
  if (i < n) {
    int v = rp[i] + boff[blockIdx.x];
    rp[i] = v;
    cursor[i] = v;
  }
}

__global__ void k_fill(const int* __restrict__ esrc, const int* __restrict__ edst,
                       const int* __restrict__ etype, int* __restrict__ cursor,
                       unsigned int* __restrict__ sorted, int E) {
  int e = blockIdx.x * blockDim.x + threadIdx.x;
  if (e >= E) return;
  int d = edst[e];
  int pos = atomicAdd(cursor + d, 1);
  sorted[pos] = (unsigned int)esrc[e] | ((unsigned int)etype[e] << 28);
}

// Y = Xbf @ WT2^T, M=rowsPad N=1280 K=256, Y bf16 [rowsPad][1280].
// m97 structure: 128x128 tile (16 MFMA : 8 ds_read per step), 2-phase dbuf,
// GLL16 staging, one barrier/step, 2-way-max XOR swizzle, XCD-chunked swizzle.
__global__ __launch_bounds__(256) void k_gemm(
    const unsigned short* __restrict__ Xbf, const unsigned short* __restrict__ WT2,
    unsigned short* __restrict__ Y, int rowsPad) {
  __shared__ unsigned short lds_a[2][128 * BK];   // 2 x 8KB
  __shared__ unsigned short lds_b[2][128 * BK];   // 2 x 8KB
  int tid = threadIdx.x;
  int wave = tid >> 6, lane = tid & 63;

  // bijective chunked XCD swizzle
  int nwg = gridDim.x, orig = blockIdx.x;
  int q = nwg >> 3, r = nwg & 7;
  int xcd = orig & 7, lin = orig >> 3;
  int wgid = (xcd < r ? xcd * (q + 1) : r * (q + 1) + (xcd - r) * q) + lin;
  int mblk = wgid / 10, nblk = wgid - mblk * 10;
  int row0 = mblk * 128, col0 = nblk * 128;
  int wr = wave >> 1, wc = wave & 1, lcol = lane & 15;

  // staging: each tile 8KB = 8 chunks of 1KB; wave stages chunks 2w,2w+1 of A and B
  const unsigned short* aSrc[2];
  const unsigned short* bSrc[2];
  int ldsOfs[2];
#pragma unroll
  for (int c2 = 0; c2 < 2; ++c2) {
    int off = (wave * 2 + c2) * 1024 + lane * 16;
    int rr = off >> 6;                                  // tile row 0..127
    int lg8 = (((off >> 4) & 3) ^ ((rr >> 1) & 3)) * 8; // inverse-swizzled src granule
    aSrc[c2] = Xbf + (size_t)(row0 + rr) * C + lg8;
    bSrc[c2] = WT2 + (size_t)(col0 + rr) * C + lg8;
    ldsOfs[c2] = (wave * 2 + c2) * 1024;
  }

  // ds_read byte offsets (swizzled): 8-row period covers all 8 16B slots -> 2-way max
  int aoff[4], boff[4];
  int kb = (lane >> 4) * 16;
#pragma unroll
  for (int i = 0; i < 4; ++i) {
    int ar = wr * 64 + i * 16 + lcol;
    aoff[i] = ar * 64 + (kb ^ (((ar >> 1) & 3) << 4));
    int bc = wc * 64 + i * 16 + lcol;
    boff[i] = bc * 64 + (kb ^ (((bc >> 1) & 3) << 4));
  }

  f32x4 acc[4][4];
#pragma unroll
  for (int i = 0; i < 4; ++i)
#pragma unroll
    for (int j = 0; j < 4; ++j) {
      f32x4 z; z[0] = 0.f; z[1] = 0.f; z[2] = 0.f; z[3] = 0.f;
      acc[i][j] = z;
    }

  auto stage = [&](int buf, int ks) {
    int kofs = ks * BK;
#pragma unroll
    for (int c2 = 0; c2 < 2; ++c2) {
      GLL16(aSrc[c2] + kofs, (char*)&lds_a[buf][0] + ldsOfs[c2]);
      GLL16(bSrc[c2] + kofs, (char*)&lds_b[buf][0] + ldsOfs[c2]);
    }
  };

  stage(0, 0);
  __syncthreads();   // tile 0 resident

#pragma unroll 2
  for (int ks = 0; ks < 8; ++ks) {          // K = 256 / 32
    int cur = ks & 1;
    if (ks + 1 < 8) stage(cur ^ 1, ks + 1); // next-tile loads in flight
    bf16x8 af[4], bfr[4];
#pragma unroll
    for (int i = 0; i < 4; ++i) {
      af[i]  = *reinterpret_cast<const bf16x8*>((const char*)&lds_a[cur][0] + aoff[i]);
      bfr[i] = *reinterpret_cast<const bf16x8*>((const char*)&lds_b[cur][0] + boff[i]);
    }
#pragma unroll
    for (int mr = 0; mr < 4; ++mr)
#pragma unroll
      for (int nc = 0; nc < 4; ++nc)
        acc[mr][nc] = __builtin_amdgcn_mfma_f32_16x16x32_bf16(af[mr], bfr[nc], acc[mr][nc], 0, 0, 0);
    __syncthreads();
  }

  // bf16 store (scalar u16; 4x32B segments per wave-store)
  int lrow4 = (lane >> 4) * 4;
#pragma unroll
  for (int mr = 0; mr < 4; ++mr) {
#pragma unroll
    for (int reg = 0; reg < 4; ++reg) {
      int rowg = row0 + wr * 64 + mr * 16 + lrow4 + reg;
#pragma unroll
      for (int nc = 0; nc < 4; ++nc) {
        int colg = col0 + wc * 64 + nc * 16 + lcol;
        Y[(size_t)rowg * NOUT + colg] = f2bf(acc[mr][nc][reg]);
      }
    }
  }
}

#define ACC(u, v)                                                            \
  do {                                                                       \
    float f0 = bf2f((v).x), f1 = bf2f((v).y), f2 = bf2f((v).z), f3 = bf2f((v).w); \
    switch ((u) >> 28) {                                                     \
      case 0: a0.x += f0; a0.y += f1; a0.z += f2; a0.w += f3; ++c0; break;   \
      case 1: a1.x += f0; a1.y += f1; a1.z += f2; a1.w += f3; ++c1; break;   \
      case 2: a2.x += f0; a2.y += f1; a2.z += f2; a2.w += f3; ++c2; break;   \
      default: a3.x += f0; a3.y += f1; a3.z += f2; a3.w += f3; ++c3; break;  \
    }                                                                        \
  } while (0)

// Fused gather+gate. One wave per dst: mean per-relation Y slices (+root+bias)
// -> u0; a = sigmoid(dot(u0,w1)+ax2+ab); out = tanh(u0)*a + X*(1-a).
// Edge index: Y slice addr = src*320 + (r+1)*64 + lane (us4 units).
__global__ void k_gg(const unsigned short* __restrict__ Y,
                     const unsigned int* __restrict__ sorted,
                     const int* __restrict__ rp, const float* __restrict__ X,
                     const float* __restrict__ bias, const float* __restrict__ attw,
                     const float* __restrict__ abp, const float* __restrict__ ax2,
                     float* __restrict__ out, int N) {
  int wave = threadIdx.x >> 6, lane = threadIdx.x & 63;
  int dst = blockIdx.x * 4 + wave;
  if (dst >= N) return;
  const us4* Yv = reinterpret_cast<const us4*>(Y);   // row stride 320 us4

  float4 a0 = make_float4(0, 0, 0, 0), a1 = a0, a2 = a0, a3 = a0;
  int c0 = 0, c1 = 0, c2 = 0, c3 = 0;
  int s = rp[dst], e2 = rp[dst + 1];

#define YIDX(u) ((size_t)((u) & 0x0FFFFFFFu) * 320 + (((u) >> 28) + 1) * 64 + lane)
  int e = s;
  for (; e + 8 <= e2; e += 8) {
    unsigned int u0 = sorted[e],     u1 = sorted[e + 1], u2 = sorted[e + 2], u3 = sorted[e + 3];
    unsigned int u4 = sorted[e + 4], u5 = sorted[e + 5], u6 = sorted[e + 6], u7 = sorted[e + 7];
    us4 v0 = Yv[YIDX(u0)], v1 = Yv[YIDX(u1)], v2 = Yv[YIDX(u2)], v3 = Yv[YIDX(u3)];
    us4 v4 = Yv[YIDX(u4)], v5 = Yv[YIDX(u5)], v6 = Yv[YIDX(u6)], v7 = Yv[YIDX(u7)];
    ACC(u0, v0); ACC(u1, v1); ACC(u2, v2); ACC(u3, v3);
    ACC(u4, v4); ACC(u5, v5); ACC(u6, v6); ACC(u7, v7);
  }
  for (; e + 4 <= e2; e += 4) {
    unsigned int u0 = sorted[e], u1 = sorted[e + 1], u2 = sorted[e + 2], u3 = sorted[e + 3];
    us4 v0 = Yv[YIDX(u0)], v1 = Yv[YIDX(u1)], v2 = Yv[YIDX(u2)], v3 = Yv[YIDX(u3)];
    ACC(u0, v0); ACC(u1, v1); ACC(u2, v2); ACC(u3, v3);
  }
  for (; e < e2; ++e) {
    unsigned int u = sorted[e];
    us4 v = Yv[YIDX(u)];
    ACC(u, v);
  }
#undef YIDX

  float s0 = 1.0f / (float)max(c0, 1);
  float s1 = 1.0f / (float)max(c1, 1);
  float s2 = 1.0f / (float)max(c2, 1);
  float s3 = 1.0f / (float)max(c3, 1);
  us4 rt = Yv[(size_t)dst * 320 + lane];              // root slice (m=0)
  float4 bi = reinterpret_cast<const float4*>(bias)[lane];
  float4 w1 = reinterpret_cast<const float4*>(attw)[lane];
  float4 u0;
  u0.x = a0.x * s0 + a1.x * s1 + a2.x * s2 + a3.x * s3 + bf2f(rt.x) + bi.x;
  u0.y = a0.y * s0 + a1.y * s1 + a2.y * s2 + a3.y * s3 + bf2f(rt.y) + bi.y;
  u0.z = a0.z * s0 + a1.z * s1 + a2.z * s2 + a3.z * s3 + bf2f(rt.z) + bi.z;
  u0.w = a0.w * s0 + a1.w * s1 + a2.w * s2 + a3.w * s3 + bf2f(rt.w) + bi.w;

  float p = u0.x * w1.x + u0.y * w1.y + u0.z * w1.z + u0.w * w1.w;
#pragma unroll
  for (int m2 = 32; m2 >= 1; m2 >>= 1) p += __shfl_xor(p, m2);
  float a = 1.0f / (1.0f + expf(-(p + ax2[dst] + abp[0])));
  float b = 1.0f - a;
  float4 x4 = reinterpret_cast<const float4*>(X + (size_t)dst * C)[lane];
  float4 h;
  h.x = tanhf(u0.x) * a + x4.x * b;
  h.y = tanhf(u0.y) * a + x4.y * b;
  h.z = tanhf(u0.z) * a + x4.z * b;
  h.w = tanhf(u0.w) * a + x4.w * b;
  reinterpret_cast<float4*>(out + (size_t)dst * C)[lane] = h;
}

extern "C" void kernel_launch(void* const* d_in, const int* in_sizes, int n_in,
                              void* d_out, int out_size, void* d_ws, size_t ws_size,
                              hipStream_t stream) {
  const float* X     = (const float*)d_in[0];
  const int*   eidx  = (const int*)d_in[1];
  const int*   etype = (const int*)d_in[2];
  const float* rel   = (const float*)d_in[3];
  const float* root  = (const float*)d_in[4];
  const float* bias  = (const float*)d_in[5];
  const float* attw  = (const float*)d_in[6];
  const float* ab    = (const float*)d_in[7];
  float* out = (float*)d_out;

  int N = in_sizes[0] / C;                // 50000
  int E = in_sizes[2];                    // 800000
  int rowsPad = ((N + 127) / 128) * 128;  // 50048
  const int* esrc = eidx;
  const int* edst = eidx + E;

  char* w = (char*)d_ws;
  size_t off = 0;
  auto alloc = [&](size_t bytes) -> void* {
    void* p = w + off;
    off += (bytes + 255) & ~(size_t)255;
    return p;
  };
  unsigned short* Y    = (unsigned short*)alloc((size_t)rowsPad * NOUT * 2);  // 128 MB
  unsigned short* Xbf  = (unsigned short*)alloc((size_t)rowsPad * C * 2);
  unsigned short* WT2  = (unsigned short*)alloc((size_t)NOUT * C * 2);
  float* ax2  = (float*)alloc((size_t)rowsPad * 4);
  int* cnt    = (int*)alloc((size_t)N * 4);
  int* rp     = (int*)alloc((size_t)(N + 1) * 4);
  int* cursor = (int*)alloc((size_t)N * 4);
  int* bsum   = (int*)alloc(1024);
  int* boffb  = (int*)alloc(1024);
  unsigned int* sorted = (unsigned int*)alloc((size_t)E * 4);

  int preBlocks = NOUT + (rowsPad >> 2) + (N + 255) / 256;
  k_pre<<<preBlocks, 256, 0, stream>>>(X, rel, root, attw, Xbf, WT2, ax2, cnt, N, rowsPad);
  k_gemm<<<(rowsPad / 128) * 10, 256, 0, stream>>>(Xbf, WT2, Y, rowsPad);
  k_hist<<<(E + 255) / 256, 256, 0, stream>>>(edst, cnt, E);
  int NB = (N + 511) / 512;
  k_scan1<<<NB, 512, 0, stream>>>(cnt, rp, bsum, N);
  k_scan2<<<1, 64, 0, stream>>>(bsum, boffb, rp, NB, N);
  k_scan3<<<NB, 512, 0, stream>>>(rp, boffb, cursor, N);
  k_fill<<<(E + 255) / 256, 256, 0, stream>>>(esrc, edst, etype, cursor, sorted, E);
  k_gg<<<(N + 3) / 4, 256, 0, stream>>>(Y, sorted, rp, X, bias, attw, ab, ax2, out, N);
}